// Round 2
// baseline (80.957 us; speedup 1.0000x reference)
//
#include <hip/hip_runtime.h>

#define NUM_WIRES 4
#define NUM_LAYERS 2
#define ELEMS 4  // batch elements per thread (sequential, unroll-1)

// R6 == R5 resubmission (both prior rounds died on container-acquisition
// infra failure; no counters produced, so the ELEMS=4 theory is still the
// pending experiment).
//
// R5: R4 skeleton (1 elem/thread, VGPR<=64, constants via VMEM float4 +
// readfirstlane into SGPRs, native v_sin/v_cos trig) + ONE change:
// 4 elements per thread processed SEQUENTIALLY (#pragma unroll 1), so the
// ~85-inst batch-uniform constant preamble (14 loads + 56 rfl) is paid once
// per 4 elements instead of once per element (~-10% inst/elem). A rotating
// one-ahead prefetch of the next x float4 hides the load latency under the
// ~550-inst compute of the current element. Coalescing unchanged: lane i
// touches element base + i, stepping by 256 per iteration.
//
// ws layout (floats):
//  [ 0..15]  layer-0 per wire w: {A=cx*cz, B=cx*sz, C=sx*sz, D=sx*cz}
//  [16..23]  layer-1 RX per wire: {cos, sin}
//  [24..55]  layer-1 combined RZ diagonal: 16 x {dr, di}
//
// State layout: amp[i], bit3=wire0 ... bit0=wire3 (reference (B,2,2,2,2) order).

#define INV_4PI 0.07957747154594767f  // 0.5 / (2*pi): sin(0.5x) = v_sin(x * INV_4PI)

__global__ void gate_prep(const float* __restrict__ params, float* __restrict__ g) {
    const int t = threadIdx.x;
    if (t < 4) {
        const float p0 = params[t * 2 + 0];  // RZ
        const float p1 = params[t * 2 + 1];  // RX
        float cz, sz, cx, sx;
        __sincosf(0.5f * p0, &sz, &cz);
        __sincosf(0.5f * p1, &sx, &cx);
        g[t * 4 + 0] = cx * cz;
        g[t * 4 + 1] = cx * sz;
        g[t * 4 + 2] = sx * sz;
        g[t * 4 + 3] = sx * cz;
    } else if (t < 8) {
        const int w = t - 4;
        const float p1 = params[(NUM_WIRES + w) * 2 + 1];
        float cx, sx;
        __sincosf(0.5f * p1, &sx, &cx);
        g[16 + w * 2] = cx;
        g[17 + w * 2] = sx;
    } else if (t >= 16 && t < 32) {
        const int i = t - 16;
        float dr = 1.f, di = 0.f;
        for (int w = 0; w < NUM_WIRES; ++w) {
            const float p0 = params[(NUM_WIRES + w) * 2 + 0];
            float c, s;
            __sincosf(0.5f * p0, &s, &c);
            const float sg = ((i >> (3 - w)) & 1) ? s : -s;
            const float ndr = dr * c - di * sg;
            const float ndi = dr * sg + di * c;
            dr = ndr; di = ndi;
        }
        g[24 + i * 2] = dr;
        g[25 + i * 2] = di;
    }
}

__device__ __forceinline__ float rfl(float v) {
    return __int_as_float(__builtin_amdgcn_readfirstlane(__float_as_int(v)));
}

__device__ __forceinline__ void cmul(float ar, float ai, float br, float bi,
                                     float& orr, float& oi) {
    orr = fmaf(ar, br, -(ai * bi));
    oi  = fmaf(ar, bi,   ai * br);
}

template <int CM, int TM>
__device__ __forceinline__ void cnot(float zr[16], float zi[16]) {
#pragma unroll
    for (int i = 0; i < 16; ++i) {
        if ((i & CM) && !(i & TM)) {
            const int j = i | TM;
            float t;
            t = zr[i]; zr[i] = zr[j]; zr[j] = t;
            t = zi[i]; zi[i] = zi[j]; zi[j] = t;
        }
    }
}

__global__ __launch_bounds__(256) void qsim_kernel(const float* __restrict__ x,
                                                   const float* __restrict__ gf,
                                                   float* __restrict__ out, int batch) {
    const int b0 = blockIdx.x * (256 * ELEMS) + threadIdx.x;

    // Pull all 56 batch-uniform gate constants into SGPRs (R4-proven path).
    // Paid ONCE per ELEMS elements now.
    float G[56];
#pragma unroll
    for (int k = 0; k < 14; ++k) {
        const float4 v = reinterpret_cast<const float4*>(gf)[k];
        G[4 * k + 0] = rfl(v.x);
        G[4 * k + 1] = rfl(v.y);
        G[4 * k + 2] = rfl(v.z);
        G[4 * k + 3] = rfl(v.w);
    }

    float4 xv = make_float4(0.f, 0.f, 0.f, 0.f);
    if (b0 < batch) xv = reinterpret_cast<const float4*>(x)[b0];

#pragma unroll 1
    for (int k = 0; k < ELEMS; ++k) {
        const int b = b0 + k * 256;
        if (b >= batch) break;

        // Prefetch next element's input before the long compute chain.
        const int bn = b + 256;
        float4 xn = make_float4(0.f, 0.f, 0.f, 0.f);
        if (k + 1 < ELEMS && bn < batch) xn = reinterpret_cast<const float4*>(x)[bn];

        // Layer-0: fused gate applied to each wire's RY(x)|0> = (c,s) factor.
        // Native HW trig: sin(0.5*x) = v_sin_f32(x * INV_4PI), likewise cos.
        float fr[4][2], fi[4][2];
        {
            const float xs[4] = {xv.x, xv.y, xv.z, xv.w};
#pragma unroll
            for (int w = 0; w < 4; ++w) {
                const float r = xs[w] * INV_4PI;
                const float s = __builtin_amdgcn_sinf(r);
                const float c = __builtin_amdgcn_cosf(r);
                const float A = G[w * 4 + 0], B = G[w * 4 + 1];
                const float C = G[w * 4 + 2], D = G[w * 4 + 3];
                fr[w][0] = fmaf(A, c, C * s);      // u00r*c + u01r*s
                fi[w][0] = fmaf(-B, c, -(D * s));  // u00i*c + u01i*s
                fr[w][1] = fmaf(A, s, -(C * c));   // u10r*c + u11r*s
                fi[w][1] = fmaf(B, s, -(D * c));   // u10i*c + u11i*s
            }
        }

        // Complex outer product: z = (f0 (x) f1) (x) (f2 (x) f3)
        float mr[4], mi[4], nr[4], ni[4];
#pragma unroll
        for (int p = 0; p < 2; ++p)
#pragma unroll
            for (int q = 0; q < 2; ++q) {
                cmul(fr[0][p], fi[0][p], fr[1][q], fi[1][q], mr[p * 2 + q], mi[p * 2 + q]);
                cmul(fr[2][p], fi[2][p], fr[3][q], fi[3][q], nr[p * 2 + q], ni[p * 2 + q]);
            }
        float zr[16], zi[16];
#pragma unroll
        for (int i = 0; i < 16; ++i)
            cmul(mr[i >> 2], mi[i >> 2], nr[i & 3], ni[i & 3], zr[i], zi[i]);

        // Layer-0 CNOT ring (free register permutation)
        cnot<8, 4>(zr, zi);
        cnot<4, 2>(zr, zi);
        cnot<2, 1>(zr, zi);
        cnot<1, 8>(zr, zi);

        // Layer-1 combined RZ diagonal
#pragma unroll
        for (int i = 0; i < 16; ++i) {
            const float dr = G[24 + i * 2], di = G[25 + i * 2];
            const float ar = zr[i], ai = zi[i];
            zr[i] = fmaf(dr, ar, -(di * ai));
            zi[i] = fmaf(dr, ai,   di * ar);
        }

        // Layer-1 RX per wire: new_a = c*a - i*s*b -> (c*ar + s*bi, c*ai - s*br)
#pragma unroll
        for (int w = 0; w < 4; ++w) {
            const float c = G[16 + w * 2], s = G[17 + w * 2];
            const int M = 8 >> w;
#pragma unroll
            for (int i = 0; i < 16; ++i) {
                if (!(i & M)) {
                    const int j = i | M;
                    const float ar = zr[i], ai = zi[i];
                    const float br = zr[j], bi = zi[j];
                    zr[i] = fmaf(c, ar,   s * bi);
                    zi[i] = fmaf(c, ai, -(s * br));
                    zr[j] = fmaf(c, br,   s * ai);
                    zi[j] = fmaf(c, bi, -(s * ar));
                }
            }
        }

        // Layer-1 CNOT ring
        cnot<8, 4>(zr, zi);
        cnot<4, 2>(zr, zi);
        cnot<2, 1>(zr, zi);
        cnot<1, 8>(zr, zi);

        // Probabilities and <Z_w> via sum/difference tree
        float p[16];
#pragma unroll
        for (int i = 0; i < 16; ++i) p[i] = fmaf(zr[i], zr[i], zi[i] * zi[i]);

        float d0[8], s1[8];
#pragma unroll
        for (int kk = 0; kk < 8; ++kk) {
            d0[kk] = p[2 * kk] - p[2 * kk + 1];
            s1[kk] = p[2 * kk] + p[2 * kk + 1];
        }
        const float e3 = ((d0[0] + d0[1]) + (d0[2] + d0[3])) + ((d0[4] + d0[5]) + (d0[6] + d0[7]));
        const float e2 = ((s1[0] - s1[1]) + (s1[2] - s1[3])) + ((s1[4] - s1[5]) + (s1[6] - s1[7]));
        float s2[4];
#pragma unroll
        for (int kk = 0; kk < 4; ++kk) s2[kk] = s1[2 * kk] + s1[2 * kk + 1];
        const float e1 = (s2[0] - s2[1]) + (s2[2] - s2[3]);
        const float e0 = (s2[0] + s2[1]) - (s2[2] + s2[3]);

        reinterpret_cast<float4*>(out)[b] = make_float4(e0, e1, e2, e3);

        xv = xn;
    }
}

extern "C" void kernel_launch(void* const* d_in, const int* in_sizes, int n_in,
                              void* d_out, int out_size, void* d_ws, size_t ws_size,
                              hipStream_t stream) {
    const float* x = (const float*)d_in[0];        // (B, 4) float32
    const float* params = (const float*)d_in[1];   // (2, 4, 2) float32
    float* out = (float*)d_out;                    // (B, 4) float32
    float* g = (float*)d_ws;                       // 56 floats of gate constants
    const int batch = in_sizes[0] / NUM_WIRES;

    gate_prep<<<1, 64, 0, stream>>>(params, g);
    const int per_block = 256 * ELEMS;
    const int blocks = (batch + per_block - 1) / per_block;
    qsim_kernel<<<blocks, 256, 0, stream>>>(x, g, out, batch);
}

// Round 3
// 78.641 us; speedup vs baseline: 1.0294x; 1.0294x over previous
//
#include <hip/hip_runtime.h>

#define NUM_WIRES 4
#define NUM_LAYERS 2
#define ELEMS 4  // batch elements per thread (sequential, unroll-1)

// R7: single-kernel fusion. Round-2 counters showed qsim_kernel < 43 us
// (absent from top-5 dispatches; harness 268MB memsets at 43-45 us outrank
// it) while measured total is 81 us -> the dependent gate_prep<<<1,64>>>
// launch + serialization is a large fixed overhead. This round folds
// gate_prep into qsim_kernel: first 32 lanes of each block recompute the
// 56 gate constants into LDS (~150 inst, once per block), __syncthreads,
// then the R4-proven constant path runs from LDS instead of VMEM:
// 14 x ds_read_b128 (uniform addr -> broadcast) + 56 x readfirstlane
// into SGPRs. Everything else identical to R5/R6 (ELEMS=4, native
// v_sin/v_cos for batch trig, 16-amp register state).
//
// LDS g[] layout (floats):
//  [ 0..15]  layer-0 per wire w: {A=cx*cz, B=cx*sz, C=sx*sz, D=sx*cz}
//  [16..23]  layer-1 RX per wire: {cos, sin}
//  [24..55]  layer-1 combined RZ diagonal: 16 x {dr, di}
//
// State layout: amp[i], bit3=wire0 ... bit0=wire3 (reference (B,2,2,2,2) order).

#define INV_4PI 0.07957747154594767f  // 0.5 / (2*pi): sin(0.5x) = v_sin(x * INV_4PI)

__device__ __forceinline__ float rfl(float v) {
    return __int_as_float(__builtin_amdgcn_readfirstlane(__float_as_int(v)));
}

__device__ __forceinline__ void cmul(float ar, float ai, float br, float bi,
                                     float& orr, float& oi) {
    orr = fmaf(ar, br, -(ai * bi));
    oi  = fmaf(ar, bi,   ai * br);
}

template <int CM, int TM>
__device__ __forceinline__ void cnot(float zr[16], float zi[16]) {
#pragma unroll
    for (int i = 0; i < 16; ++i) {
        if ((i & CM) && !(i & TM)) {
            const int j = i | TM;
            float t;
            t = zr[i]; zr[i] = zr[j]; zr[j] = t;
            t = zi[i]; zi[i] = zi[j]; zi[j] = t;
        }
    }
}

__global__ __launch_bounds__(256) void qsim_kernel(const float* __restrict__ x,
                                                   const float* __restrict__ params,
                                                   float* __restrict__ out, int batch) {
    __shared__ float g[64];  // 56 used

    // --- Per-block gate prep (first wave only; ~150 inst, once per block) ---
    const int t = threadIdx.x;
    if (t < 32) {
        if (t < 4) {
            const float p0 = params[t * 2 + 0];  // RZ
            const float p1 = params[t * 2 + 1];  // RX
            float cz, sz, cx, sx;
            __sincosf(0.5f * p0, &sz, &cz);
            __sincosf(0.5f * p1, &sx, &cx);
            g[t * 4 + 0] = cx * cz;
            g[t * 4 + 1] = cx * sz;
            g[t * 4 + 2] = sx * sz;
            g[t * 4 + 3] = sx * cz;
        } else if (t < 8) {
            const int w = t - 4;
            const float p1 = params[(NUM_WIRES + w) * 2 + 1];
            float cx, sx;
            __sincosf(0.5f * p1, &sx, &cx);
            g[16 + w * 2] = cx;
            g[17 + w * 2] = sx;
        } else if (t >= 16) {
            const int i = t - 16;
            float dr = 1.f, di = 0.f;
            for (int w = 0; w < NUM_WIRES; ++w) {
                const float p0 = params[(NUM_WIRES + w) * 2 + 0];
                float c, s;
                __sincosf(0.5f * p0, &s, &c);
                const float sg = ((i >> (3 - w)) & 1) ? s : -s;
                const float ndr = dr * c - di * sg;
                const float ndi = dr * sg + di * c;
                dr = ndr; di = ndi;
            }
            g[24 + i * 2] = dr;
            g[25 + i * 2] = di;
        }
    }
    __syncthreads();

    // --- Pull all 56 batch-uniform constants into SGPRs via LDS broadcast ---
    float G[56];
#pragma unroll
    for (int k = 0; k < 14; ++k) {
        const float4 v = reinterpret_cast<const float4*>(g)[k];
        G[4 * k + 0] = rfl(v.x);
        G[4 * k + 1] = rfl(v.y);
        G[4 * k + 2] = rfl(v.z);
        G[4 * k + 3] = rfl(v.w);
    }

    const int b0 = blockIdx.x * (256 * ELEMS) + threadIdx.x;
    float4 xv = make_float4(0.f, 0.f, 0.f, 0.f);
    if (b0 < batch) xv = reinterpret_cast<const float4*>(x)[b0];

#pragma unroll 1
    for (int k = 0; k < ELEMS; ++k) {
        const int b = b0 + k * 256;
        if (b >= batch) break;

        // Prefetch next element's input before the long compute chain.
        const int bn = b + 256;
        float4 xn = make_float4(0.f, 0.f, 0.f, 0.f);
        if (k + 1 < ELEMS && bn < batch) xn = reinterpret_cast<const float4*>(x)[bn];

        // Layer-0: fused gate applied to each wire's RY(x)|0> = (c,s) factor.
        // Native HW trig: sin(0.5*x) = v_sin_f32(x * INV_4PI), likewise cos.
        float fr[4][2], fi[4][2];
        {
            const float xs[4] = {xv.x, xv.y, xv.z, xv.w};
#pragma unroll
            for (int w = 0; w < 4; ++w) {
                const float r = xs[w] * INV_4PI;
                const float s = __builtin_amdgcn_sinf(r);
                const float c = __builtin_amdgcn_cosf(r);
                const float A = G[w * 4 + 0], B = G[w * 4 + 1];
                const float C = G[w * 4 + 2], D = G[w * 4 + 3];
                fr[w][0] = fmaf(A, c, C * s);      // u00r*c + u01r*s
                fi[w][0] = fmaf(-B, c, -(D * s));  // u00i*c + u01i*s
                fr[w][1] = fmaf(A, s, -(C * c));   // u10r*c + u11r*s
                fi[w][1] = fmaf(B, s, -(D * c));   // u10i*c + u11i*s
            }
        }

        // Complex outer product: z = (f0 (x) f1) (x) (f2 (x) f3)
        float mr[4], mi[4], nr[4], ni[4];
#pragma unroll
        for (int p = 0; p < 2; ++p)
#pragma unroll
            for (int q = 0; q < 2; ++q) {
                cmul(fr[0][p], fi[0][p], fr[1][q], fi[1][q], mr[p * 2 + q], mi[p * 2 + q]);
                cmul(fr[2][p], fi[2][p], fr[3][q], fi[3][q], nr[p * 2 + q], ni[p * 2 + q]);
            }
        float zr[16], zi[16];
#pragma unroll
        for (int i = 0; i < 16; ++i)
            cmul(mr[i >> 2], mi[i >> 2], nr[i & 3], ni[i & 3], zr[i], zi[i]);

        // Layer-0 CNOT ring (free register permutation)
        cnot<8, 4>(zr, zi);
        cnot<4, 2>(zr, zi);
        cnot<2, 1>(zr, zi);
        cnot<1, 8>(zr, zi);

        // Layer-1 combined RZ diagonal
#pragma unroll
        for (int i = 0; i < 16; ++i) {
            const float dr = G[24 + i * 2], di = G[25 + i * 2];
            const float ar = zr[i], ai = zi[i];
            zr[i] = fmaf(dr, ar, -(di * ai));
            zi[i] = fmaf(dr, ai,   di * ar);
        }

        // Layer-1 RX per wire: new_a = c*a - i*s*b -> (c*ar + s*bi, c*ai - s*br)
#pragma unroll
        for (int w = 0; w < 4; ++w) {
            const float c = G[16 + w * 2], s = G[17 + w * 2];
            const int M = 8 >> w;
#pragma unroll
            for (int i = 0; i < 16; ++i) {
                if (!(i & M)) {
                    const int j = i | M;
                    const float ar = zr[i], ai = zi[i];
                    const float br = zr[j], bi = zi[j];
                    zr[i] = fmaf(c, ar,   s * bi);
                    zi[i] = fmaf(c, ai, -(s * br));
                    zr[j] = fmaf(c, br,   s * ai);
                    zi[j] = fmaf(c, bi, -(s * ar));
                }
            }
        }

        // Layer-1 CNOT ring
        cnot<8, 4>(zr, zi);
        cnot<4, 2>(zr, zi);
        cnot<2, 1>(zr, zi);
        cnot<1, 8>(zr, zi);

        // Probabilities and <Z_w> via sum/difference tree
        float p[16];
#pragma unroll
        for (int i = 0; i < 16; ++i) p[i] = fmaf(zr[i], zr[i], zi[i] * zi[i]);

        float d0[8], s1[8];
#pragma unroll
        for (int kk = 0; kk < 8; ++kk) {
            d0[kk] = p[2 * kk] - p[2 * kk + 1];
            s1[kk] = p[2 * kk] + p[2 * kk + 1];
        }
        const float e3 = ((d0[0] + d0[1]) + (d0[2] + d0[3])) + ((d0[4] + d0[5]) + (d0[6] + d0[7]));
        const float e2 = ((s1[0] - s1[1]) + (s1[2] - s1[3])) + ((s1[4] - s1[5]) + (s1[6] - s1[7]));
        float s2[4];
#pragma unroll
        for (int kk = 0; kk < 4; ++kk) s2[kk] = s1[2 * kk] + s1[2 * kk + 1];
        const float e1 = (s2[0] - s2[1]) + (s2[2] - s2[3]);
        const float e0 = (s2[0] + s2[1]) - (s2[2] + s2[3]);

        reinterpret_cast<float4*>(out)[b] = make_float4(e0, e1, e2, e3);

        xv = xn;
    }
}

extern "C" void kernel_launch(void* const* d_in, const int* in_sizes, int n_in,
                              void* d_out, int out_size, void* d_ws, size_t ws_size,
                              hipStream_t stream) {
    const float* x = (const float*)d_in[0];        // (B, 4) float32
    const float* params = (const float*)d_in[1];   // (2, 4, 2) float32
    float* out = (float*)d_out;                    // (B, 4) float32
    const int batch = in_sizes[0] / NUM_WIRES;

    const int per_block = 256 * ELEMS;
    const int blocks = (batch + per_block - 1) / per_block;
    qsim_kernel<<<blocks, 256, 0, stream>>>(x, params, out, batch);
}